// Round 8
// baseline (107.368 us; speedup 1.0000x reference)
//
#include <hip/hip_runtime.h>
#include <math.h>

// Problem constants (from reference): DT=1, V_LAMBDA=1e-4, V_RIDGE=1e-4
#define LAM3  1e-4f   // V_LAMBDA / DT^6
#define RIDGE 1e-4f
#define NN    64      // N
#define NP    65      // N+1

// PROBE ROUND 2: REP=8 so the dispatch (~66us) definitively exceeds the ~41us
// fill kernels and surfaces in the rocprof top-5 with its own counters.
// REP=4 missed the cutoff by 0.2us. Body is IDENTICAL to the r6 champion;
// stores are idempotent; the memory clobber forces faithful re-execution.
// REP=1 restores the production kernel.
#define REP 8

// (D3^T D3) band values for Np=65 (third-difference smoother), boundary-truncated.
__device__ __forceinline__ float d3_diag(int f) {
    if (f == 0 || f == 64) return 1.f;
    if (f == 1 || f == 63) return 10.f;
    if (f == 2 || f == 62) return 19.f;
    return 20.f;
}
__device__ __forceinline__ float d3_off1(int f) { // [f][f-1], valid f>=1
    if (f == 1 || f == 64) return -3.f;
    if (f == 2 || f == 63) return -12.f;
    return -15.f;
}
__device__ __forceinline__ float d3_off2(int f) { // [f][f-2], valid f>=2
    if (f == 2 || f == 64) return 3.f;
    return 6.f;
}
// [f][f-3] == -1 everywhere it exists (f>=3)

__global__ __launch_bounds__(64, 1) void alpamayo_banded_solve(
    const float* __restrict__ dxy,    // [B,64,2]
    const float* __restrict__ theta,  // [B,65]
    const float* __restrict__ v0,     // [B]
    float* __restrict__ out,          // [B,65]
    int B)
{
    // Per-thread column layout: no cross-thread sharing -> no barriers needed.
    __shared__ float4 Lrec[NN][64];   // 64 KiB

    const int tid = threadIdx.x;
    const int b = blockIdx.x * 64 + tid;
    if (b >= B) return;

    #pragma unroll 1
    for (int rep = 0; rep < REP; ++rep) {
        asm volatile("" ::: "memory");   // faithful re-execution each rep

        const float* th = theta + (long)b * NP;
        const float4* dx4 = (const float4*)(dxy + (long)b * (2 * NN));
        const float v0b = v0[b];

        // ---- Preload ALL inputs into registers (batched, one vmcnt drain) ----
        float dxf[2 * NN];
        #pragma unroll
        for (int j = 0; j < 32; ++j) {
            const float4 q = dx4[j];
            dxf[4 * j + 0] = q.x; dxf[4 * j + 1] = q.y;
            dxf[4 * j + 2] = q.z; dxf[4 * j + 3] = q.w;
        }
        float thr[NP];
        #pragma unroll
        for (int f = 0; f < NP; ++f) thr[f] = th[f];

        float* outp = out + (long)b * NP;
        outp[0] = v0b;                       // fire early, off-chain

        // ---- FUSED: sincos + e + rhs + banded Cholesky + forward substitution ----
        float z[NN];
        float cp, sp;
        __sincosf(thr[0], &sp, &cp);
        float xc = dxf[0], yc = dxf[1];

        float p1L1 = 0.f, p1L2 = 0.f, p2L1 = 0.f;
        float rd1 = 0.f, rd2 = 0.f, rd3 = 0.f;
        float z1 = 0.f, z2 = 0.f, z3 = 0.f;

        #pragma unroll
        for (int i = 0; i < NN; ++i) {
            const int f = i + 1;
            float cf, sf;
            __sincosf(thr[f], &sf, &cf);
            const float e  = cf * cp + sf * sp;            // cos(theta_f - theta_{f-1})
            const float xs = (f < NN) ? dxf[2 * f]     : 0.f;
            const float ys = (f < NN) ? dxf[2 * f + 1] : 0.f;
            float rr = 2.f * (cf * (xc + xs) + sf * (yc + ys));
            // v0 corrections, compile-time selected by the unroll.
            if (i == 0) rr -= (e + LAM3 * -3.f) * v0b;
            if (i == 1) rr -= (LAM3 *  3.f) * v0b;
            if (i == 2) rr -= (LAM3 * -1.f) * v0b;

            const float a0 = (f == NN ? 1.f : 2.f) + LAM3 * d3_diag(f) + RIDGE;
            const float a1 = e + LAM3 * d3_off1(f);
            const float a2 = LAM3 * d3_off2(f);

            const float Li3 = (-LAM3) * rd3;               // killed by rd3=0 for i<3
            const float Li2 = (a2 - Li3 * p2L1) * rd2;     // killed by rd2=0 for i<2
            const float Li1 = (a1 - Li3 * p1L2 - Li2 * p1L1) * rd1;
            const float dg  = a0 - Li3 * Li3 - Li2 * Li2 - Li1 * Li1;
            const float rd0 = __builtin_amdgcn_rsqf(dg);
            const float zi  = (rr - Li3 * z3 - Li2 * z2 - Li1 * z1) * rd0;

            Lrec[i][tid] = make_float4(Li1, Li2, Li3, rd0);
            z[i] = zi;

            p2L1 = p1L1; p1L1 = Li1; p1L2 = Li2;
            rd3 = rd2; rd2 = rd1; rd1 = rd0;
            z3 = z2; z2 = z1; z1 = zi;
            cp = cf; sp = sf; xc = xs; yc = ys;
        }

        // ---- Back substitution ----
        float r1L1 = 0.f, r1L2 = 0.f, r1L3 = 0.f;
        float r2L2 = 0.f, r2L3 = 0.f;
        float r3L3 = 0.f;
        float y1 = 0.f, y2 = 0.f, y3 = 0.f;

        #pragma unroll
        for (int i = NN - 1; i >= 0; --i) {
            const float4 rec = Lrec[i][tid];
            const float yi = (z[i] - r1L1 * y1 - r2L2 * y2 - r3L3 * y3) * rec.w;
            outp[1 + i] = yi;
            r3L3 = r2L3; r2L3 = r1L3; r2L2 = r1L2;
            r1L1 = rec.x; r1L2 = rec.y; r1L3 = rec.z;
            y3 = y2; y2 = y1; y1 = yi;
        }
    }
}

extern "C" void kernel_launch(void* const* d_in, const int* in_sizes, int n_in,
                              void* d_out, int out_size, void* d_ws, size_t ws_size,
                              hipStream_t stream) {
    const float* dxy   = (const float*)d_in[0];   // [B,64,2]
    const float* theta = (const float*)d_in[1];   // [B,65]
    const float* v0    = (const float*)d_in[2];   // [B]
    float* out = (float*)d_out;                   // [B,65]
    const int B = in_sizes[2];
    const int blocks = (B + 63) / 64;
    alpamayo_banded_solve<<<blocks, 64, 0, stream>>>(dxy, theta, v0, out, B);
}

// Round 9
// 66.651 us; speedup vs baseline: 1.6109x; 1.6109x over previous
//
#include <hip/hip_runtime.h>
#include <math.h>

// Problem constants (from reference): DT=1, V_LAMBDA=1e-4, V_RIDGE=1e-4
#define LAM3  1e-4f   // V_LAMBDA / DT^6
#define RIDGE 1e-4f
#define NN    64      // N
#define NP    65      // N+1

// Rolled-by-8 structure. Cost model from the REP probes (r7/r8):
//   dur_us = 0.8 + 2*kernel;  kernel = cold(~90cy per 64B I-line from HBM,
//   L1I+L2+L3 flushed every dispatch by the 268MB re-poison fill) + warm(3.1us).
// Full unroll = ~20KB text = ~28us cold. This version: ~4KB text, inputs
// streamed global->registers one 8-iter block ahead (batched, unconditional),
// Lrec float4 (L1,L2,rd,z) in LDS, back-sub uses r3L3 == -lam*rd[i] identity.

// Global input loads for 8-iteration block bn_ (f = 8bn_+1 .. 8bn_+8) into the
// named double-buffer regs tn0..tn7 / dn0..dn7. Unconditional; dn7 clamped at
// the last block (col 128 OOB -> read col 126, masked at consume).
#define LOADB(bn_) do {                                                    \
    const int fb = 8 * (bn_) + 1;                                          \
    tn0 = thp[fb + 0]; tn1 = thp[fb + 1]; tn2 = thp[fb + 2];               \
    tn3 = thp[fb + 3]; tn4 = thp[fb + 4]; tn5 = thp[fb + 5];               \
    tn6 = thp[fb + 6]; tn7 = thp[fb + 7];                                  \
    const int cb = 16 * (bn_) + 2;                                         \
    dn0 = *(const float2*)(dxp + cb +  0);                                 \
    dn1 = *(const float2*)(dxp + cb +  2);                                 \
    dn2 = *(const float2*)(dxp + cb +  4);                                 \
    dn3 = *(const float2*)(dxp + cb +  6);                                 \
    dn4 = *(const float2*)(dxp + cb +  8);                                 \
    dn5 = *(const float2*)(dxp + cb + 10);                                 \
    dn6 = *(const float2*)(dxp + cb + 12);                                 \
    const int c7 = (cb + 14 <= 126) ? (cb + 14) : 126;                     \
    dn7 = *(const float2*)(dxp + c7);                                      \
} while (0)

// One fused setup+Cholesky+forward-sub iteration. J is a literal (folds),
// bi is wave-uniform (boundary selects become SALU s_cselect).
// d3 bands: diag 20 / off1 -15 / off2 6 interior; boundaries:
//   f=1:(10,-3,6) f=2:(19,-12,3) f=62:(19,-15,6) f=63:(10,-12,6) f=64:(1,-3,3)
#define FWD(J, TC, DC) do {                                                \
    float cf, sf; __sincosf((TC), &sf, &cf);                               \
    const float e = cf * cp + sf * sp;                                     \
    float xs = (DC).x, ys = (DC).y;                                        \
    if ((J) == 7) { if (bi == 7) { xs = 0.f; ys = 0.f; } }  /* f==64 */    \
    float rr = 2.f * (cf * (xc + xs) + sf * (yc + ys));                    \
    if ((J) == 0) { if (bi == 0) rr -= (e - 3.f * LAM3) * v0b; }           \
    if ((J) == 1) { if (bi == 0) rr -= ( 3.f * LAM3) * v0b; }              \
    if ((J) == 2) { if (bi == 0) rr -= (-LAM3) * v0b; }                    \
    float dv = 20.f, o1 = -15.f, o2v = 6.f, base0 = 2.f;                   \
    if ((J) == 0) { if (bi == 0) { dv = 10.f; o1 = -3.f; } }               \
    if ((J) == 1) { if (bi == 0) { dv = 19.f; o1 = -12.f; o2v = 3.f; } }   \
    if ((J) == 5) { if (bi == 7) { dv = 19.f; } }                          \
    if ((J) == 6) { if (bi == 7) { dv = 10.f; o1 = -12.f; } }              \
    if ((J) == 7) { if (bi == 7) { dv = 1.f; o1 = -3.f; o2v = 3.f;         \
                                   base0 = 1.f; } }                        \
    const float a0 = base0 + LAM3 * dv + RIDGE;                            \
    const float a1 = e + LAM3 * o1;                                        \
    const float a2 = LAM3 * o2v;                                           \
    const float Li3 = (-LAM3) * rd3;              /* rd3=0 kills i<3 */    \
    const float Li2 = (a2 - Li3 * p2L1) * rd2;    /* rd2=0 kills i<2 */    \
    const float Li1 = (a1 - Li3 * p1L2 - Li2 * p1L1) * rd1;                \
    const float dgv = a0 - Li3 * Li3 - Li2 * Li2 - Li1 * Li1;              \
    const float rd0 = __builtin_amdgcn_rsqf(dgv);                          \
    const float zi  = (rr - Li3 * z3 - Li2 * z2 - Li1 * z1) * rd0;         \
    Lrec[8 * bi + (J)][tid] = make_float4(Li1, Li2, rd0, zi);              \
    p2L1 = p1L1; p1L1 = Li1; p1L2 = Li2;                                   \
    rd3 = rd2; rd2 = rd1; rd1 = rd0;                                       \
    z3 = z2; z2 = z1; z1 = zi;                                             \
    cp = cf; sp = sf; xc = xs; yc = ys;                                    \
} while (0)

// Back-substitution step. Q = (L1[i], L2[i], rd[i], z[i]).
// yi = (z - L1[i+1]*y1 - L2[i+2]*y2 + lam*rd[i]*y3) * rd[i]
// (r3L3 == L3[i+3] == -lam*rd[i] — identity validated in rounds 3/4.)
#define BCK(J, Q) do {                                                     \
    const float t0 = (Q).w - l1c * y1;                                     \
    const float t1 = t0 - l2c2 * y2;                                       \
    const float t2 = t1 + LAM3 * (Q).z * y3;                               \
    const float yi = t2 * (Q).z;                                           \
    outp[1 + 8 * bi + (J)] = yi;                                           \
    l1c = (Q).x; l2c2 = l2c1; l2c1 = (Q).y;                                \
    y3 = y2; y2 = y1; y1 = yi;                                             \
} while (0)

__global__ __launch_bounds__(64, 1) void alpamayo_banded_solve(
    const float* __restrict__ dxy,    // [B,64,2]
    const float* __restrict__ theta,  // [B,65]
    const float* __restrict__ v0,     // [B]
    float* __restrict__ out,          // [B,65]
    int B)
{
    // Per-lane column layout; no cross-lane sharing -> no barriers.
    __shared__ float4 Lrec[NN][64];   // (L1, L2, rd, z) — 64 KiB

    const int tid = threadIdx.x;
    int b = blockIdx.x * 64 + tid;
    if (b >= B) b = B - 1;            // clamp tail: duplicate rows, benign dup writes

    const float*  thp = theta + (long)b * NP;
    const float*  dxp = dxy   + (long)b * (2 * NN);
    float*       outp = out   + (long)b * NP;
    const float v0b = v0[b];

    // ---- Prologue: first-block prefetch + initial carries (one batched wait) ----
    float  tn0, tn1, tn2, tn3, tn4, tn5, tn6, tn7;
    float2 dn0, dn1, dn2, dn3, dn4, dn5, dn6, dn7;
    LOADB(0);
    float cp, sp;
    __sincosf(thp[0], &sp, &cp);
    float xc, yc;
    { const float2 d0 = *(const float2*)(dxp); xc = d0.x; yc = d0.y; }
    outp[0] = v0b;                    // off-chain

    float p1L1 = 0.f, p1L2 = 0.f, p2L1 = 0.f;
    float rd1 = 0.f, rd2 = 0.f, rd3 = 0.f;
    float z1 = 0.f, z2 = 0.f, z3 = 0.f;

    // ---- Forward: 8 blocks of 8, inputs double-buffered one block ahead ----
    #pragma unroll 1
    for (int bi = 0; bi < 8; ++bi) {
        const float  tc0 = tn0, tc1 = tn1, tc2 = tn2, tc3 = tn3;
        const float  tc4 = tn4, tc5 = tn5, tc6 = tn6, tc7 = tn7;
        const float2 dc0 = dn0, dc1 = dn1, dc2 = dn2, dc3 = dn3;
        const float2 dc4 = dn4, dc5 = dn5, dc6 = dn6, dc7 = dn7;
        const int bn = (bi < 7) ? bi + 1 : 7;   // last block re-loads itself (L1-hot)
        LOADB(bn);

        FWD(0, tc0, dc0); FWD(1, tc1, dc1); FWD(2, tc2, dc2); FWD(3, tc3, dc3);
        FWD(4, tc4, dc4); FWD(5, tc5, dc5); FWD(6, tc6, dc6); FWD(7, tc7, dc7);
    }

    // ---- Backward: 8 blocks of 8, batched ds_read_b128 per block ----
    float l1c = 0.f, l2c1 = 0.f, l2c2 = 0.f;
    float y1 = 0.f, y2 = 0.f, y3 = 0.f;

    #pragma unroll 1
    for (int bi = 7; bi >= 0; --bi) {
        const float4 q7 = Lrec[8 * bi + 7][tid];
        const float4 q6 = Lrec[8 * bi + 6][tid];
        const float4 q5 = Lrec[8 * bi + 5][tid];
        const float4 q4 = Lrec[8 * bi + 4][tid];
        const float4 q3 = Lrec[8 * bi + 3][tid];
        const float4 q2 = Lrec[8 * bi + 2][tid];
        const float4 q1 = Lrec[8 * bi + 1][tid];
        const float4 q0 = Lrec[8 * bi + 0][tid];

        BCK(7, q7); BCK(6, q6); BCK(5, q5); BCK(4, q4);
        BCK(3, q3); BCK(2, q2); BCK(1, q1); BCK(0, q0);
    }
}

extern "C" void kernel_launch(void* const* d_in, const int* in_sizes, int n_in,
                              void* d_out, int out_size, void* d_ws, size_t ws_size,
                              hipStream_t stream) {
    const float* dxy   = (const float*)d_in[0];   // [B,64,2]
    const float* theta = (const float*)d_in[1];   // [B,65]
    const float* v0    = (const float*)d_in[2];   // [B]
    float* out = (float*)d_out;                   // [B,65]
    const int B = in_sizes[2];
    const int blocks = (B + 63) / 64;
    alpamayo_banded_solve<<<blocks, 64, 0, stream>>>(dxy, theta, v0, out, B);
}